// Round 1
// baseline (321.003 us; speedup 1.0000x reference)
//
#include <hip/hip_runtime.h>

// Problem constants: x [32,64,64,64] f32, emb [64,1024] f32
// N = 131072 pixels, D = 64, K = 1024
// out = [ result: 8388608 f32 ][ argmin-as-f32: 131072 ]

__global__ void e2_kernel(const float* __restrict__ emb, float* __restrict__ e2) {
    int k = blockIdx.x * 256 + threadIdx.x;   // 4 blocks x 256 = 1024
    float s = 0.f;
#pragma unroll
    for (int d = 0; d < 64; ++d) {
        float v = emb[d * 1024 + k];
        s = fmaf(v, v, s);
    }
    e2[k] = s;
}

__launch_bounds__(256)
__global__ void vq_kernel(const float* __restrict__ x,
                          const float* __restrict__ emb,
                          const float* __restrict__ e2,
                          float* __restrict__ outq,
                          float* __restrict__ outidx) {
    __shared__ float sx[64 * 64];   // x tile   [d][p], p contiguous
    __shared__ float se[64 * 64];   // emb tile [d][k], k contiguous (reused as reduce scratch)
    __shared__ int samin[64];

    const int tx = threadIdx.x;
    const int n0 = blockIdx.x * 64;       // 64 consecutive pixels, same (b,h) row
    const int bb = n0 >> 12;              // n0 / 4096
    const int hw = n0 & 4095;             // h*64 + w0
    const float* xbase = x + bb * 262144 + hw;   // + d*4096 + p

    // stage x tile: 64 d x 64 p, coalesced float4
    for (int i = tx; i < 1024; i += 256) {
        int d = i >> 4;
        int p4 = (i & 15) << 2;
        *(float4*)(sx + d * 64 + p4) = *(const float4*)(xbase + d * 4096 + p4);
    }

    const int pg = tx & 15;   // pixel group: pixels pg*4 .. pg*4+3
    const int kg = tx >> 4;   // k group within pass: ks kg*4 .. kg*4+3

    float best[4];
    int bestk[4];
#pragma unroll
    for (int pi = 0; pi < 4; ++pi) { best[pi] = 3.4e38f; bestk[pi] = 0; }

    for (int pass = 0; pass < 16; ++pass) {
        const int k0 = pass << 6;
        __syncthreads();   // previous pass finished reading se (also covers sx staging, pass 0)
        for (int i = tx; i < 1024; i += 256) {
            int d = i >> 4;
            int k4 = (i & 15) << 2;
            *(float4*)(se + d * 64 + k4) = *(const float4*)(emb + d * 1024 + k0 + k4);
        }
        __syncthreads();

        float acc[4][4];
#pragma unroll
        for (int pi = 0; pi < 4; ++pi)
#pragma unroll
            for (int ki = 0; ki < 4; ++ki) acc[pi][ki] = 0.f;

#pragma unroll 8
        for (int d = 0; d < 64; ++d) {
            float4 xv4 = *(const float4*)(sx + d * 64 + (pg << 2));
            float4 ev4 = *(const float4*)(se + d * 64 + (kg << 2));
            float xv[4] = {xv4.x, xv4.y, xv4.z, xv4.w};
            float ev[4] = {ev4.x, ev4.y, ev4.z, ev4.w};
#pragma unroll
            for (int pi = 0; pi < 4; ++pi)
#pragma unroll
                for (int ki = 0; ki < 4; ++ki)
                    acc[pi][ki] = fmaf(xv[pi], ev[ki], acc[pi][ki]);
        }

        // dist = ||e||^2 - 2*x.e   (per-pixel ||x||^2 omitted: argmin-invariant)
        float4 e2v4 = *(const float4*)(e2 + k0 + (kg << 2));
        float e2v[4] = {e2v4.x, e2v4.y, e2v4.z, e2v4.w};
#pragma unroll
        for (int ki = 0; ki < 4; ++ki) {
            int k = k0 + (kg << 2) + ki;
#pragma unroll
            for (int pi = 0; pi < 4; ++pi) {
                float dist = fmaf(-2.f, acc[pi][ki], e2v[ki]);
                if (dist < best[pi]) { best[pi] = dist; bestk[pi] = k; }  // strict <: keeps lowest k
            }
        }
    }

    // cross-thread argmin reduce over the 16 k-groups (reuse se as scratch)
    __syncthreads();
    float* rval = se;
    int* ridx = (int*)(se + 1024);
#pragma unroll
    for (int pi = 0; pi < 4; ++pi) {
        rval[(kg * 16 + pg) * 4 + pi] = best[pi];
        ridx[(kg * 16 + pg) * 4 + pi] = bestk[pi];
    }
    __syncthreads();
    if (tx < 64) {
        int pg2 = tx >> 2, pi2 = tx & 3;
        float bv = 3.4e38f;
        int bk = 0x7fffffff;
        for (int g = 0; g < 16; ++g) {
            float v = rval[(g * 16 + pg2) * 4 + pi2];
            int kk = ridx[(g * 16 + pg2) * 4 + pi2];
            if (v < bv || (v == bv && kk < bk)) { bv = v; bk = kk; }
        }
        samin[tx] = bk;
        outidx[n0 + tx] = (float)bk;   // argmin stored as float (f32 output buffer)
    }
    __syncthreads();

    // gather codebook rows -> output, coalesced over p
    const int p = tx & 63;
    const int drow = tx >> 6;
    const int amin = samin[p];
    float* obase = outq + bb * 262144 + hw + p;
#pragma unroll
    for (int it = 0; it < 16; ++it) {
        int d = (it << 2) + drow;
        obase[d * 4096] = emb[d * 1024 + amin];
    }
}

extern "C" void kernel_launch(void* const* d_in, const int* in_sizes, int n_in,
                              void* d_out, int out_size, void* d_ws, size_t ws_size,
                              hipStream_t stream) {
    const float* x = (const float*)d_in[0];
    const float* emb = (const float*)d_in[1];
    float* outq = (float*)d_out;
    float* outidx = outq + 8388608;   // 32*64*64*64
    float* e2 = (float*)d_ws;         // 1024 floats scratch

    e2_kernel<<<4, 256, 0, stream>>>(emb, e2);
    vq_kernel<<<2048, 256, 0, stream>>>(x, emb, e2, outq, outidx);
}